// Round 7
// baseline (331.680 us; speedup 1.0000x reference)
//
#include <hip/hip_runtime.h>
#include <stdint.h>

#define N 4096
#define D 1024
#define MARGIN 0.1f
#define BM 128
#define BN 128
#define BK 64
#define NPROD 256                 // producer blocks, 16 rows each
#define FLAG_MAGIC 0x5EEDF00Du   // != 0xAAAAAAAA ws poison

typedef __attribute__((ext_vector_type(8))) __bf16 bf16x8;
typedef __attribute__((ext_vector_type(4))) __bf16 bf16x4;
typedef __attribute__((ext_vector_type(4))) float f32x4;

// Single non-cooperative kernel, producer/consumer split by blockIdx.
//  blocks [0,256):   producers — normalize 16 rows (W,O) to bf16 + fp32 diag,
//                    then release-store flags[p]=MAGIC. Block 0 zeroes d_out.
//  blocks [256,1280): consumers — spin (acquire) on the 8 producer flags of
//                    row-block by, bx, and 0 (d_out zero), then run the
//                    proven R2 GEMM (55.5 us, VGPR 88, 0 bank conflicts).
// Safety: producers have the LOWEST block IDs -> dispatched to CUs first ->
// they can never be starved by spinning consumers (in-order CP dispatch).
// Flags live in re-poisoned ws: 0xAAAAAAAA != MAGIC, so no zero-init needed.
// R5 lesson kept: NO min-occupancy launch_bounds (unified VGPR/AGPR file:
// acc[4][4] = 64 AGPR + ~88 VGPR; forcing 4 waves/SIMD strangles the K-loop).
__global__ __launch_bounds__(256) void fused_pc_kernel(
    const float* __restrict__ W, const float* __restrict__ O,
    __bf16* __restrict__ Wn, __bf16* __restrict__ On,
    float* __restrict__ dvec, uint32_t* __restrict__ flags,
    float* __restrict__ out) {
  const int t = threadIdx.x;
  const int wv = t >> 6, ln = t & 63;

  if (blockIdx.x < NPROD) {
    // ---------------- Producer: 16 rows, wave-per-row x4 ----------------
    const int p = blockIdx.x;
    if (p == 0 && t == 0) *out = 0.0f;  // d_out re-poisoned each call
    #pragma unroll
    for (int i = 0; i < 4; ++i) {
      const int row = p * 16 + i * 4 + wv;
      const float4* Wr = (const float4*)(W + (size_t)row * D);
      const float4* Or = (const float4*)(O + (size_t)row * D);
      float4 w[4], o[4];
      float sw = 0.f, so = 0.f, sd = 0.f;
      #pragma unroll
      for (int c = 0; c < 4; ++c) {
        w[c] = Wr[ln + c * 64];
        o[c] = Or[ln + c * 64];
        sw += w[c].x * w[c].x + w[c].y * w[c].y + w[c].z * w[c].z + w[c].w * w[c].w;
        so += o[c].x * o[c].x + o[c].y * o[c].y + o[c].z * o[c].z + o[c].w * o[c].w;
        sd += w[c].x * o[c].x + w[c].y * o[c].y + w[c].z * o[c].z + w[c].w * o[c].w;
      }
      #pragma unroll
      for (int off = 1; off < 64; off <<= 1) {
        sw += __shfl_xor(sw, off, 64);
        so += __shfl_xor(so, off, 64);
        sd += __shfl_xor(sd, off, 64);
      }
      const float inw = 1.0f / sqrtf(sw);
      const float ino = 1.0f / sqrtf(so);
      if (ln == 0) dvec[row] = sd * inw * ino;
      bf16x4* Wo = (bf16x4*)(Wn + (size_t)row * D);
      bf16x4* Oo = (bf16x4*)(On + (size_t)row * D);
      #pragma unroll
      for (int c = 0; c < 4; ++c) {
        bf16x4 vw, vo;
        vw.x = (__bf16)(w[c].x * inw); vw.y = (__bf16)(w[c].y * inw);
        vw.z = (__bf16)(w[c].z * inw); vw.w = (__bf16)(w[c].w * inw);
        vo.x = (__bf16)(o[c].x * ino); vo.y = (__bf16)(o[c].y * ino);
        vo.z = (__bf16)(o[c].z * ino); vo.w = (__bf16)(o[c].w * ino);
        Wo[ln + c * 64] = vw;
        Oo[ln + c * 64] = vo;
      }
    }
    __threadfence();   // device-scope: publish Wn/On/dvec (and *out for p==0)
    __syncthreads();   // all waves' writes fenced before the flag
    if (t == 0)
      __hip_atomic_store(&flags[p], FLAG_MAGIC, __ATOMIC_RELEASE,
                         __HIP_MEMORY_SCOPE_AGENT);
    return;
  }

  // ---------------- Consumer: wait for row-blocks by, bx, 0 --------------
  const int tile = blockIdx.x - NPROD;
  const int bx = tile & 31, by = tile >> 5;
  if (t == 0) {
    const int bases[3] = {0, by * 8, bx * 8};
    #pragma unroll
    for (int b = 0; b < 3; ++b)
      for (int j = 0; j < 8; ++j)
        while (__hip_atomic_load(&flags[bases[b] + j], __ATOMIC_ACQUIRE,
                                 __HIP_MEMORY_SCOPE_AGENT) != FLAG_MAGIC)
          __builtin_amdgcn_s_sleep(2);
  }
  __syncthreads();  // block proceeds only after t0's acquire (L1 invalidated)

  // ---------------- R2/R6 GEMM, byte-identical ---------------------------
  __shared__ __bf16 ldsA[BM * BK];  // 16 KB
  __shared__ __bf16 ldsB[BN * BK];  // 16 KB
  const int wm = wv >> 1, wn = wv & 1;   // 2x2 wave grid, 64x64 per wave
  const int lrow = ln & 15;
  const int quad = ln >> 4;
  const int l7 = lrow & 7;

  f32x4 acc[4][4] = {};

  const __bf16* Ag = Wn + (size_t)(by * BM) * D;
  const __bf16* Bg = On + (size_t)(bx * BN) * D;

  for (int kt = 0; kt < D / BK; ++kt) {
    #pragma unroll
    for (int c = 0; c < 4; ++c) {
      const int e = c * 2048 + t * 8;        // LDS element slot (fixed by lane)
      const int r = e >> 6;                  // tile row
      const int chunk_l = (e >> 3) & 7;      // LDS chunk slot within row
      const int col = (chunk_l ^ (r & 7)) * 8;  // swizzled global chunk
      __builtin_amdgcn_global_load_lds(
          (const __attribute__((address_space(1))) void*)(Ag + (size_t)r * D + kt * BK + col),
          (__attribute__((address_space(3))) void*)(ldsA + e), 16, 0, 0);
      __builtin_amdgcn_global_load_lds(
          (const __attribute__((address_space(1))) void*)(Bg + (size_t)r * D + kt * BK + col),
          (__attribute__((address_space(3))) void*)(ldsB + e), 16, 0, 0);
    }
    __syncthreads();
    #pragma unroll
    for (int kk = 0; kk < BK; kk += 32) {
      const int kb = kk >> 3;
      bf16x8 af[4], bfr[4];
      #pragma unroll
      for (int mi = 0; mi < 4; ++mi) {
        const int rr = wm * 64 + mi * 16 + lrow;
        af[mi] = *(const bf16x8*)(ldsA + rr * BK + (((quad + kb) ^ l7) << 3));
      }
      #pragma unroll
      for (int ni = 0; ni < 4; ++ni) {
        const int cc = wn * 64 + ni * 16 + lrow;
        bfr[ni] = *(const bf16x8*)(ldsB + cc * BK + (((quad + kb) ^ l7) << 3));
      }
      #pragma unroll
      for (int mi = 0; mi < 4; ++mi)
        #pragma unroll
        for (int ni = 0; ni < 4; ++ni)
          acc[mi][ni] = __builtin_amdgcn_mfma_f32_16x16x32_bf16(
              af[mi], bfr[ni], acc[mi][ni], 0, 0, 0);
    }
    __syncthreads();
  }

  // Epilogue: C/D layout col=lane&15, row=quad*4+reg (verified m89/m91)
  float lsum = 0.0f;
  #pragma unroll
  for (int mi = 0; mi < 4; ++mi) {
    const int gibase = by * BM + wm * 64 + mi * 16 + quad * 4;
    #pragma unroll
    for (int r = 0; r < 4; ++r) {
      const int gi = gibase + r;
      const float di = dvec[gi];  // fp32 diagonal (accurate)
      #pragma unroll
      for (int ni = 0; ni < 4; ++ni) {
        const int gj = bx * BN + wn * 64 + ni * 16 + lrow;
        const float s = acc[mi][ni][r];
        lsum += (gi == gj) ? (1.0f - s) : fmaxf(MARGIN - s + di, 0.0f);
      }
    }
  }
  #pragma unroll
  for (int off = 32; off; off >>= 1) lsum += __shfl_down(lsum, off, 64);
  __shared__ float bsum[4];
  if (ln == 0) bsum[wv] = lsum;
  __syncthreads();
  if (t == 0) {
    const float tot = (bsum[0] + bsum[1] + bsum[2] + bsum[3]) *
                      (1.0f / ((float)N * (float)N));
    atomicAdd(out, tot);
  }
}

extern "C" void kernel_launch(void* const* d_in, const int* in_sizes, int n_in,
                              void* d_out, int out_size, void* d_ws, size_t ws_size,
                              hipStream_t stream) {
  const float* W = (const float*)d_in[0];  // wsi_embeddings (N,1,D)
  const float* O = (const float*)d_in[1];  // omic_embeddings (N,1,D)
  __bf16* Wn = (__bf16*)d_ws;                        // 8 MB
  __bf16* On = Wn + (size_t)N * D;                   // 8 MB
  float* dvec = (float*)(On + (size_t)N * D);        // 16 KB
  uint32_t* flags = (uint32_t*)(dvec + N);           // 1 KB (poison != MAGIC)
  float* out = (float*)d_out;

  void (*kp)(const float*, const float*, __bf16*, __bf16*, float*, uint32_t*, float*) =
      fused_pc_kernel;
  (void)kp;
  fused_pc_kernel<<<NPROD + (N / BM) * (N / BN), 256, 0, stream>>>(
      W, O, Wn, On, dvec, flags, out);
}

// Round 8
// 124.232 us; speedup vs baseline: 2.6698x; 2.6698x over previous
//
#include <hip/hip_runtime.h>
#include <stdint.h>

#define N 4096
#define D 1024
#define MARGIN 0.1f
#define BM 64
#define BN 128
#define BK 64

typedef __attribute__((ext_vector_type(8))) __bf16 bf16x8;
typedef __attribute__((ext_vector_type(4))) __bf16 bf16x4;
typedef __attribute__((ext_vector_type(4))) float f32x4;

// Kernel 1: one wave per row (4 rows/block), fp32 norms + diagonal dot,
// butterfly shfl_xor reduce, write normalized bf16 rows; block 0 zeroes d_out.
__global__ __launch_bounds__(256) void prep_kernel(
    const float* __restrict__ W, const float* __restrict__ O,
    __bf16* __restrict__ Wn, __bf16* __restrict__ On,
    float* __restrict__ dvec, float* __restrict__ out) {
  const int wv = threadIdx.x >> 6, ln = threadIdx.x & 63;
  const int row = blockIdx.x * 4 + wv;
  if (blockIdx.x == 0 && threadIdx.x == 0) *out = 0.0f;
  const float4* Wr = (const float4*)(W + (size_t)row * D);
  const float4* Or = (const float4*)(O + (size_t)row * D);
  float4 w[4], o[4];
  float sw = 0.f, so = 0.f, sd = 0.f;
  #pragma unroll
  for (int c = 0; c < 4; ++c) {
    w[c] = Wr[ln + c * 64];
    o[c] = Or[ln + c * 64];
    sw += w[c].x * w[c].x + w[c].y * w[c].y + w[c].z * w[c].z + w[c].w * w[c].w;
    so += o[c].x * o[c].x + o[c].y * o[c].y + o[c].z * o[c].z + o[c].w * o[c].w;
    sd += w[c].x * o[c].x + w[c].y * o[c].y + w[c].z * o[c].z + w[c].w * o[c].w;
  }
  #pragma unroll
  for (int off = 1; off < 64; off <<= 1) {
    sw += __shfl_xor(sw, off, 64);
    so += __shfl_xor(so, off, 64);
    sd += __shfl_xor(sd, off, 64);
  }
  const float inw = 1.0f / sqrtf(sw);
  const float ino = 1.0f / sqrtf(so);
  if (ln == 0) dvec[row] = sd * inw * ino;
  bf16x4* Wo = (bf16x4*)(Wn + (size_t)row * D);
  bf16x4* Oo = (bf16x4*)(On + (size_t)row * D);
  #pragma unroll
  for (int c = 0; c < 4; ++c) {
    bf16x4 vw, vo;
    vw.x = (__bf16)(w[c].x * inw); vw.y = (__bf16)(w[c].y * inw);
    vw.z = (__bf16)(w[c].z * inw); vw.w = (__bf16)(w[c].w * inw);
    vo.x = (__bf16)(o[c].x * ino); vo.y = (__bf16)(o[c].y * ino);
    vo.z = (__bf16)(o[c].z * ino); vo.w = (__bf16)(o[c].w * ino);
    Wo[ln + c * 64] = vw;
    Oo[ln + c * 64] = vo;
  }
}

// Kernel 2: 64x128-tile bf16 MFMA GEMM + fused loss epilogue.
// R8 thesis: R6's 128x128 was LATENCY-bound (pipe-busy ~10us of 55us;
// regs 88 VGPR + 64 AGPR = 152 unified -> 3 waves/SIMD = 12 waves/CU).
// Halving the accumulator (32 AGPR/wave) targets 4 waves/SIMD = 16
// waves/CU + 4 tiles in flight + shorter per-iter chain. 2048 blocks =
// exactly 2 rounds at 4 blocks/CU. XOR chunk swizzle retained (R2:
// SQ_LDS_BANK_CONFLICT == 0). NO min-occupancy launch_bounds (R5 lesson).
__global__ __launch_bounds__(256) void gemm_loss_kernel(
    const __bf16* __restrict__ Wn, const __bf16* __restrict__ On,
    const float* __restrict__ dvec, float* __restrict__ out) {
  __shared__ __bf16 ldsA[BM * BK];  // 8 KB
  __shared__ __bf16 ldsB[BN * BK];  // 16 KB
  const int bx = blockIdx.x, by = blockIdx.y;
  const int t = threadIdx.x;
  const int wv = t >> 6, ln = t & 63;
  const int wm = wv >> 1, wn = wv & 1;   // 2x2 wave grid; wave = 32x64 of C
  const int lrow = ln & 15;
  const int quad = ln >> 4;
  const int l7 = lrow & 7;

  f32x4 acc[2][4] = {};

  const __bf16* Ag = Wn + (size_t)(by * BM) * D;
  const __bf16* Bg = On + (size_t)(bx * BN) * D;

  for (int kt = 0; kt < D / BK; ++kt) {
    // A-tile: 64x64 = 4096 elems = 2 rounds of 256 lanes x 8
    #pragma unroll
    for (int c = 0; c < 2; ++c) {
      const int e = c * 2048 + t * 8;
      const int r = e >> 6;
      const int chunk_l = (e >> 3) & 7;
      const int col = (chunk_l ^ (r & 7)) * 8;  // XOR swizzle
      __builtin_amdgcn_global_load_lds(
          (const __attribute__((address_space(1))) void*)(Ag + (size_t)r * D + kt * BK + col),
          (__attribute__((address_space(3))) void*)(ldsA + e), 16, 0, 0);
    }
    // B-tile: 128x64 = 8192 elems = 4 rounds
    #pragma unroll
    for (int c = 0; c < 4; ++c) {
      const int e = c * 2048 + t * 8;
      const int r = e >> 6;
      const int chunk_l = (e >> 3) & 7;
      const int col = (chunk_l ^ (r & 7)) * 8;
      __builtin_amdgcn_global_load_lds(
          (const __attribute__((address_space(1))) void*)(Bg + (size_t)r * D + kt * BK + col),
          (__attribute__((address_space(3))) void*)(ldsB + e), 16, 0, 0);
    }
    __syncthreads();
    #pragma unroll
    for (int kk = 0; kk < BK; kk += 32) {
      const int kb = kk >> 3;
      bf16x8 af[2], bfr[4];
      #pragma unroll
      for (int mi = 0; mi < 2; ++mi) {
        const int rr = wm * 32 + mi * 16 + lrow;
        af[mi] = *(const bf16x8*)(ldsA + rr * BK + (((quad + kb) ^ l7) << 3));
      }
      #pragma unroll
      for (int ni = 0; ni < 4; ++ni) {
        const int cc = wn * 64 + ni * 16 + lrow;
        bfr[ni] = *(const bf16x8*)(ldsB + cc * BK + (((quad + kb) ^ l7) << 3));
      }
      #pragma unroll
      for (int mi = 0; mi < 2; ++mi)
        #pragma unroll
        for (int ni = 0; ni < 4; ++ni)
          acc[mi][ni] = __builtin_amdgcn_mfma_f32_16x16x32_bf16(
              af[mi], bfr[ni], acc[mi][ni], 0, 0, 0);
    }
    __syncthreads();
  }

  // Epilogue: C/D layout col=lane&15, row=quad*4+reg (verified m89/m91)
  float lsum = 0.0f;
  #pragma unroll
  for (int mi = 0; mi < 2; ++mi) {
    const int gibase = by * BM + wm * 32 + mi * 16 + quad * 4;
    #pragma unroll
    for (int r = 0; r < 4; ++r) {
      const int gi = gibase + r;
      const float di = dvec[gi];  // fp32 diagonal (accurate)
      #pragma unroll
      for (int ni = 0; ni < 4; ++ni) {
        const int gj = bx * BN + wn * 64 + ni * 16 + lrow;
        const float s = acc[mi][ni][r];
        lsum += (gi == gj) ? (1.0f - s) : fmaxf(MARGIN - s + di, 0.0f);
      }
    }
  }
  #pragma unroll
  for (int off = 32; off; off >>= 1) lsum += __shfl_down(lsum, off, 64);
  __shared__ float bsum[4];
  if (ln == 0) bsum[wv] = lsum;
  __syncthreads();
  if (t == 0) {
    const float tot = (bsum[0] + bsum[1] + bsum[2] + bsum[3]) *
                      (1.0f / ((float)N * (float)N));
    atomicAdd(out, tot);
  }
}

extern "C" void kernel_launch(void* const* d_in, const int* in_sizes, int n_in,
                              void* d_out, int out_size, void* d_ws, size_t ws_size,
                              hipStream_t stream) {
  const float* W = (const float*)d_in[0];  // wsi_embeddings (N,1,D)
  const float* O = (const float*)d_in[1];  // omic_embeddings (N,1,D)
  __bf16* Wn = (__bf16*)d_ws;                       // 8 MB
  __bf16* On = Wn + (size_t)N * D;                  // 8 MB
  float* dvec = (float*)(On + (size_t)N * D);       // 16 KB
  float* out = (float*)d_out;

  prep_kernel<<<N / 4, 256, 0, stream>>>(W, O, Wn, On, dvec, out);
  dim3 grid(N / BN, N / BM);  // (32, 64) = 2048 blocks
  gemm_loss_kernel<<<grid, 256, 0, stream>>>(Wn, On, dvec, out);
}

// Round 9
// 111.355 us; speedup vs baseline: 2.9786x; 1.1156x over previous
//
#include <hip/hip_runtime.h>
#include <stdint.h>

#define N 4096
#define D 1024            // elements per row; fp8 => 1024 bytes per row
#define MARGIN 0.1f
#define BM 128
#define BN 128
#define BKB 128           // K-slab per tile in fp8 bytes (=128 elements)

typedef __attribute__((ext_vector_type(4))) float f32x4;

// Kernel 1: one wave per row (4 rows/block): fp32 norms + diagonal dot,
// butterfly shfl_xor reduce, write normalized rows as OCP fp8 e4m3
// (v_cvt_pk_fp8_f32, 4 values packed per int). Block 0 zeroes d_out.
// d_i is kept in fp32 — the only N-correlated error path stays exact.
__global__ __launch_bounds__(256) void prep_kernel(
    const float* __restrict__ W, const float* __restrict__ O,
    uint8_t* __restrict__ Wn, uint8_t* __restrict__ On,
    float* __restrict__ dvec, float* __restrict__ out) {
  const int wv = threadIdx.x >> 6, ln = threadIdx.x & 63;
  const int row = blockIdx.x * 4 + wv;
  if (blockIdx.x == 0 && threadIdx.x == 0) *out = 0.0f;
  const float4* Wr = (const float4*)(W + (size_t)row * D);
  const float4* Or = (const float4*)(O + (size_t)row * D);
  float4 w[4], o[4];
  float sw = 0.f, so = 0.f, sd = 0.f;
  #pragma unroll
  for (int c = 0; c < 4; ++c) {
    w[c] = Wr[ln + c * 64];
    o[c] = Or[ln + c * 64];
    sw += w[c].x * w[c].x + w[c].y * w[c].y + w[c].z * w[c].z + w[c].w * w[c].w;
    so += o[c].x * o[c].x + o[c].y * o[c].y + o[c].z * o[c].z + o[c].w * o[c].w;
    sd += w[c].x * o[c].x + w[c].y * o[c].y + w[c].z * o[c].z + w[c].w * o[c].w;
  }
  #pragma unroll
  for (int off = 1; off < 64; off <<= 1) {
    sw += __shfl_xor(sw, off, 64);
    so += __shfl_xor(so, off, 64);
    sd += __shfl_xor(sd, off, 64);
  }
  const float inw = 1.0f / sqrtf(sw);
  const float ino = 1.0f / sqrtf(so);
  if (ln == 0) dvec[row] = sd * inw * ino;
  int* Wo = (int*)(Wn + (size_t)row * D);
  int* Oo = (int*)(On + (size_t)row * D);
  #pragma unroll
  for (int c = 0; c < 4; ++c) {
    int pw = __builtin_amdgcn_cvt_pk_fp8_f32(w[c].x * inw, w[c].y * inw, 0, false);
    pw = __builtin_amdgcn_cvt_pk_fp8_f32(w[c].z * inw, w[c].w * inw, pw, true);
    int po = __builtin_amdgcn_cvt_pk_fp8_f32(o[c].x * ino, o[c].y * ino, 0, false);
    po = __builtin_amdgcn_cvt_pk_fp8_f32(o[c].z * ino, o[c].w * ino, po, true);
    Wo[ln + c * 64] = pw;
    Oo[ln + c * 64] = po;
  }
}

// Kernel 2: 128x128-tile FP8 MFMA GEMM + fused contrastive-loss epilogue.
// R9 thesis: R6/R8 are DS-pipe-bound (~27us/CU busy of 55us wall: b128 frag
// reads 20.5us + staging writes 6.8us). fp8 e4m3 halves every DS byte:
// ds_read_b64 frags, BKB=128 (kt 16->8, half the barrier drains), staging
// 512->256 MB. mfma_f32_16x16x32_fp8_fp8 = same shape/FLOP as bf16 op.
// Swizzle: 16B granule g of row r stored at slot g^(r&7) -> ds_read_b64
// lands 2 lanes/bank (free, m136). NO min-occupancy bounds (R5 lesson).
__global__ __launch_bounds__(256) void gemm_loss_kernel(
    const uint8_t* __restrict__ Wn, const uint8_t* __restrict__ On,
    const float* __restrict__ dvec, float* __restrict__ out) {
  __shared__ __align__(16) uint8_t ldsA[BM * BKB];  // 16 KB
  __shared__ __align__(16) uint8_t ldsB[BN * BKB];  // 16 KB
  const int bx = blockIdx.x, by = blockIdx.y;
  const int t = threadIdx.x;
  const int wv = t >> 6, ln = t & 63;
  const int wm = wv >> 1, wn = wv & 1;   // 2x2 wave grid, 64x64 per wave
  const int lrow = ln & 15;
  const int quad = ln >> 4;
  const int l7 = lrow & 7;               // == rr&7 == cc&7 for fragment rows
  const int sub = (quad & 1) * 8;        // low/high half of a 16B granule

  f32x4 acc[4][4] = {};

  const uint8_t* Ag = Wn + (size_t)(by * BM) * D;
  const uint8_t* Bg = On + (size_t)(bx * BN) * D;

  for (int kt = 0; kt < D / BKB; ++kt) {           // 8 iterations
    // stage 128 rows x 128 B per tile = 1024 granules(16B); 256 thr x 4 rounds
    #pragma unroll
    for (int c = 0; c < 4; ++c) {
      const int g = c * 256 + t;         // granule index (fixed LDS slot)
      const int r = g >> 3;              // tile row (8 granules per row)
      const int gi = g & 7;              // granule slot within row
      const int col = (gi ^ (r & 7)) << 4;  // swizzled global byte col
      __builtin_amdgcn_global_load_lds(
          (const __attribute__((address_space(1))) void*)(Ag + (size_t)r * D + kt * BKB + col),
          (__attribute__((address_space(3))) void*)(ldsA + g * 16), 16, 0, 0);
      __builtin_amdgcn_global_load_lds(
          (const __attribute__((address_space(1))) void*)(Bg + (size_t)r * D + kt * BKB + col),
          (__attribute__((address_space(3))) void*)(ldsB + g * 16), 16, 0, 0);
    }
    __syncthreads();
    #pragma unroll
    for (int kk = 0; kk < 4; ++kk) {     // k = kk*32 within the slab
      const int gh = kk * 2 + (quad >> 1);  // 16B granule holding this octet
      long aF[4], bF[4];
      #pragma unroll
      for (int mi = 0; mi < 4; ++mi) {
        const int rr = wm * 64 + mi * 16 + lrow;
        aF[mi] = *(const long*)(ldsA + rr * BKB + ((gh ^ l7) << 4) + sub);
      }
      #pragma unroll
      for (int ni = 0; ni < 4; ++ni) {
        const int cc = wn * 64 + ni * 16 + lrow;
        bF[ni] = *(const long*)(ldsB + cc * BKB + ((gh ^ l7) << 4) + sub);
      }
      #pragma unroll
      for (int mi = 0; mi < 4; ++mi)
        #pragma unroll
        for (int ni = 0; ni < 4; ++ni)
          acc[mi][ni] = __builtin_amdgcn_mfma_f32_16x16x32_fp8_fp8(
              aF[mi], bF[ni], acc[mi][ni], 0, 0, 0);
    }
    __syncthreads();
  }

  // Epilogue: C/D layout col=lane&15, row=quad*4+reg (dtype-independent,
  // verified m89/m121; confirmed in-session by R2 absmax=0)
  float lsum = 0.0f;
  #pragma unroll
  for (int mi = 0; mi < 4; ++mi) {
    const int gibase = by * BM + wm * 64 + mi * 16 + quad * 4;
    #pragma unroll
    for (int r = 0; r < 4; ++r) {
      const int gi = gibase + r;
      const float di = dvec[gi];  // fp32 diagonal (accurate)
      #pragma unroll
      for (int ni = 0; ni < 4; ++ni) {
        const int gj = bx * BN + wn * 64 + ni * 16 + lrow;
        const float s = acc[mi][ni][r];
        lsum += (gi == gj) ? (1.0f - s) : fmaxf(MARGIN - s + di, 0.0f);
      }
    }
  }
  #pragma unroll
  for (int off = 32; off; off >>= 1) lsum += __shfl_down(lsum, off, 64);
  __shared__ float bsum[4];
  if (ln == 0) bsum[wv] = lsum;
  __syncthreads();
  if (t == 0) {
    const float tot = (bsum[0] + bsum[1] + bsum[2] + bsum[3]) *
                      (1.0f / ((float)N * (float)N));
    atomicAdd(out, tot);
  }
}

extern "C" void kernel_launch(void* const* d_in, const int* in_sizes, int n_in,
                              void* d_out, int out_size, void* d_ws, size_t ws_size,
                              hipStream_t stream) {
  const float* W = (const float*)d_in[0];  // wsi_embeddings (N,1,D)
  const float* O = (const float*)d_in[1];  // omic_embeddings (N,1,D)
  uint8_t* Wn = (uint8_t*)d_ws;                     // 4 MB fp8
  uint8_t* On = Wn + (size_t)N * D;                 // 4 MB fp8
  float* dvec = (float*)(On + (size_t)N * D);       // 16 KB
  float* out = (float*)d_out;

  prep_kernel<<<N / 4, 256, 0, stream>>>(W, O, Wn, On, dvec, out);
  dim3 grid(N / BN, N / BM);  // 32 x 32 = 1024 blocks
  gemm_loss_kernel<<<grid, 256, 0, stream>>>(Wn, On, dvec, out);
}